// Round 7
// baseline (536.491 us; speedup 1.0000x reference)
//
#include <hip/hip_runtime.h>
#include <math.h>
#include <stdint.h>

// Problem constants
#define BB   32     // batch
#define HB   16     // batch per block (b-split: 2 blocks per n-group)
#define NN   2048   // input capsules
#define KK   16     // input dim
#define CC   32     // output capsules
#define DD   32     // capsule dim
#define NCOL 1024   // CC*DD
#define NPB  8      // n per block -> 256 n-groups x 2 b-halves = 512 blocks (2/CU)
#define WT   (KK * NCOL)          // 16384 floats = one 64 KB W tile
#define WH   (8 * NCOL)           // 8192 floats = one 32 KB half tile (8 k-rows)
#define OSZ  (BB * NCOL)          // 32768 floats = one full o/partial image
#define NSLICE 8                  // reduce tree fan-in stage 1: 256 -> 8

// async global->LDS. Global addr is per-lane; LDS dest must be the
// WAVE-UNIFORM base — HW writes lane i's 16 B at base + 16*i.
__device__ __forceinline__ void dma16(const float* g, const float* l) {
    __builtin_amdgcn_global_load_lds(
        (const __attribute__((address_space(1))) void*)(uintptr_t)g,
        (__attribute__((address_space(3))) void*)(uintptr_t)l,
        16, 0, 0);
}

// One routing iteration, fused. Per n:
//   U[b,col] = sum_k u[b,n,k] * W[n,k,col]; logit[b,c] = <U, onorm>;
//   softmax over caps; opart += c*U.
// R5 (confirmed): design for the 64-VGPR budget — b-split (16 b/block) keeps
// accumulators at 16+16 floats, zero spill. R6 pipeline: half-tile double
// buffer, every DMA covered by a half-compute phase before its drain barrier.
// R6 BUG (fixed here): the last iteration's post-C DMA had no barrier before
// s_endpgm -> in-flight global_load_lds wrote into a reassigned LDS slot,
// corrupting successor blocks. Guard: no prefetch on the final iteration.
__global__ __launch_bounds__(1024)
void caps_stage(const float* __restrict__ u, const float* __restrict__ W,
                const float* __restrict__ onorm, float* __restrict__ part)
{
    __shared__ float Wh[2][WH];              // 2 x 32 KB half tiles
    __shared__ float ush[NPB * KK * HB];     // 8 KB: [n][k][b] all 8 n's
    __shared__ float logit_sh[HB * CC];      // 2 KB
    __shared__ float c_sh[HB * CC];          // 2 KB

    const int tid  = threadIdx.x;
    const int wave = tid >> 6;
    const int lane = tid & 63;
    const int bg = tid >> 8;          // 0..3 -> 4 local b's each
    const int cq = tid & 255;         // col-quad 0..255
    const int i0 = cq >> 3;           // capsule 0..31
    const int jq = cq & 7;            // d-quad
    const int b0 = bg << 2;           // local b base
    const int c0 = cq << 2;           // col base

    const int ngrp  = blockIdx.x >> 1;
    const int bhalf = blockIdx.x & 1;
    const int n0    = ngrp * NPB;
    const int bbase = bhalf * HB;     // global b offset

    const int woff = wave << 9;       // wave * 512 floats (2 KB chunk)
    const int loff = lane << 2;       // lane * 4 floats

    // DMA one 32 KB half tile (rows half*8..+7): 16 waves x 2 x 16B/lane
    auto dma_half = [&](int n, int half, int buf) {
        const float* g = W + (size_t)n * WT + half * WH + woff + loff;
        const float* l = &Wh[buf][woff];   // wave-uniform LDS base
        dma16(g, l);
        dma16(g + 256, l + 256);
    };

    // prologue: half0(n0) -> buf0; u for all 8 n (transposed [n][k][b])
    dma_half(n0, 0, 0);
    for (int idx = tid; idx < NPB * KK * HB; idx += 1024) {
        const int n = idx >> 8, rem = idx & 255, k = rem >> 4, b = rem & 15;
        ush[idx] = u[(size_t)(bbase + b) * (NN * KK) + (size_t)(n0 + n) * KK + k];
    }
    __syncthreads();                  // drains half0 DMA + ush writes
    dma_half(n0, 1, 1);               // half1(n0) in flight; drains at S1

    float opart[4][4];
#pragma unroll
    for (int bb = 0; bb < 4; ++bb)
#pragma unroll
        for (int m = 0; m < 4; ++m) opart[bb][m] = 0.f;

    for (int nn = 0; nn < NPB; ++nn) {
        const float* un = &ush[nn << 8];
        const int np = n0 + nn + 1;            // only used when nn+1 < NPB
        const bool pf = (nn + 1 < NPB);        // block-uniform prefetch guard

        float accU[4][4];
#pragma unroll
        for (int bb = 0; bb < 4; ++bb)
#pragma unroll
            for (int m = 0; m < 4; ++m) accU[bb][m] = 0.f;

        // ---- 1. compute half0: k = 0..7 from Wh[0] ----
#pragma unroll
        for (int k = 0; k < 8; ++k) {
            const float4 w  = *(const float4*)&Wh[0][k * NCOL + c0];
            const float4 ub = *(const float4*)&un[(k << 4) + b0];
            accU[0][0] = fmaf(ub.x, w.x, accU[0][0]);
            accU[0][1] = fmaf(ub.x, w.y, accU[0][1]);
            accU[0][2] = fmaf(ub.x, w.z, accU[0][2]);
            accU[0][3] = fmaf(ub.x, w.w, accU[0][3]);
            accU[1][0] = fmaf(ub.y, w.x, accU[1][0]);
            accU[1][1] = fmaf(ub.y, w.y, accU[1][1]);
            accU[1][2] = fmaf(ub.y, w.z, accU[1][2]);
            accU[1][3] = fmaf(ub.y, w.w, accU[1][3]);
            accU[2][0] = fmaf(ub.z, w.x, accU[2][0]);
            accU[2][1] = fmaf(ub.z, w.y, accU[2][1]);
            accU[2][2] = fmaf(ub.z, w.z, accU[2][2]);
            accU[2][3] = fmaf(ub.z, w.w, accU[2][3]);
            accU[3][0] = fmaf(ub.w, w.x, accU[3][0]);
            accU[3][1] = fmaf(ub.w, w.y, accU[3][1]);
            accU[3][2] = fmaf(ub.w, w.z, accU[3][2]);
            accU[3][3] = fmaf(ub.w, w.w, accU[3][3]);
        }

        __syncthreads();   // S1: drains half1(nn) DMA; all done reading Wh[0]

        // ---- 3. prefetch half0(nn+1) -> Wh[0] (drains at B, covered) ----
        if (pf) dma_half(np, 0, 0);

        // ---- 4. compute half1: k = 8..15 from Wh[1]; logits ----
#pragma unroll
        for (int k = 0; k < 8; ++k) {
            const float4 w  = *(const float4*)&Wh[1][k * NCOL + c0];
            const float4 ub = *(const float4*)&un[((k + 8) << 4) + b0];
            accU[0][0] = fmaf(ub.x, w.x, accU[0][0]);
            accU[0][1] = fmaf(ub.x, w.y, accU[0][1]);
            accU[0][2] = fmaf(ub.x, w.z, accU[0][2]);
            accU[0][3] = fmaf(ub.x, w.w, accU[0][3]);
            accU[1][0] = fmaf(ub.y, w.x, accU[1][0]);
            accU[1][1] = fmaf(ub.y, w.y, accU[1][1]);
            accU[1][2] = fmaf(ub.y, w.z, accU[1][2]);
            accU[1][3] = fmaf(ub.y, w.w, accU[1][3]);
            accU[2][0] = fmaf(ub.z, w.x, accU[2][0]);
            accU[2][1] = fmaf(ub.z, w.y, accU[2][1]);
            accU[2][2] = fmaf(ub.z, w.z, accU[2][2]);
            accU[2][3] = fmaf(ub.z, w.w, accU[2][3]);
            accU[3][0] = fmaf(ub.w, w.x, accU[3][0]);
            accU[3][1] = fmaf(ub.w, w.y, accU[3][1]);
            accU[3][2] = fmaf(ub.w, w.z, accU[3][2]);
            accU[3][3] = fmaf(ub.w, w.w, accU[3][3]);
        }

        // logits: dot with onorm (L2-resident), reduce over jq lanes
        {
            float lp[4];
#pragma unroll
            for (int bb = 0; bb < 4; ++bb) {
                const float4 on4 = *(const float4*)(
                    onorm + ((size_t)(bbase + b0 + bb) * CC + i0) * DD + (jq << 2));
                float p = accU[bb][0] * on4.x + accU[bb][1] * on4.y
                        + accU[bb][2] * on4.z + accU[bb][3] * on4.w;
                p += __shfl_xor(p, 1);
                p += __shfl_xor(p, 2);
                p += __shfl_xor(p, 4);
                lp[bb] = p;
            }
            if (jq == 0) {
#pragma unroll
                for (int bb = 0; bb < 4; ++bb)
                    logit_sh[(b0 + bb) * CC + i0] = lp[bb];
            }
        }
        __syncthreads();   // B: logits ready; drains half0(nn+1) DMA (covered)

        // ---- 6. softmax over capsules: 512 threads (b = tid>>5, cap = tid&31) ----
        if (tid < HB * CC) {
            const int b  = tid >> 5;
            const int ii = tid & 31;
            float l = logit_sh[b * CC + ii];
            float mx = l;
#pragma unroll
            for (int msk = 16; msk >= 1; msk >>= 1)
                mx = fmaxf(mx, __shfl_xor(mx, msk));
            const float e = __expf(l - mx);
            float sm = e;
#pragma unroll
            for (int msk = 16; msk >= 1; msk >>= 1)
                sm += __shfl_xor(sm, msk);
            c_sh[b * CC + ii] = e / sm;
        }
        __syncthreads();   // C: c ready; NO DMA pending here (cheap barrier)

        // ---- 8. opart += c * U; then prefetch half1(nn+1) -> Wh[1] ----
#pragma unroll
        for (int bb = 0; bb < 4; ++bb) {
            const float cc = c_sh[(b0 + bb) * CC + i0];
#pragma unroll
            for (int m = 0; m < 4; ++m)
                opart[bb][m] = fmaf(cc, accU[bb][m], opart[bb][m]);
        }
        // drains at S1 of next iter (covered by half0 compute). On the LAST
        // iteration we must NOT issue: no barrier remains before s_endpgm,
        // and an in-flight global_load_lds would write into a reassigned
        // LDS slot (R6 corruption bug).
        if (pf) dma_half(np, 1, 1);
    }

    // flush partials, coalesced float4 stores (this block's 16-b half)
    float* my = part + (size_t)ngrp * OSZ + (size_t)bbase * NCOL;
#pragma unroll
    for (int bb = 0; bb < 4; ++bb) {
        float4 v;
        v.x = opart[bb][0]; v.y = opart[bb][1];
        v.z = opart[bb][2]; v.w = opart[bb][3];
        *(float4*)&my[(b0 + bb) * NCOL + c0] = v;
    }
}

// Level-1 reduce: 256 partial images -> NSLICE slice images.
__global__ __launch_bounds__(256) void caps_reduce1(
    const float* __restrict__ part, float* __restrict__ ws2)
{
    const int gid   = blockIdx.x * 256 + threadIdx.x;     // 0..65535
    const int slice = gid >> 13;                          // 0..7
    const int q     = gid & 8191;                         // col-quad
    float4 acc = make_float4(0.f, 0.f, 0.f, 0.f);
    const float* p = part + ((size_t)slice * 32) * OSZ + (q << 2);
#pragma unroll 8
    for (int j = 0; j < 32; ++j) {
        const float4 v = *(const float4*)(p + (size_t)j * OSZ);
        acc.x += v.x; acc.y += v.y; acc.z += v.z; acc.w += v.w;
    }
    *(float4*)(ws2 + ((size_t)gid << 2)) = acc;
}

// Level-2 reduce + row op. mode 0: l2-normalize. mode 1: squash.
__global__ __launch_bounds__(256) void caps_reduce2(
    const float* __restrict__ ws2, float* __restrict__ dst, int mode)
{
    const int q = blockIdx.x * 256 + threadIdx.x;         // 0..8191
    float4 acc = make_float4(0.f, 0.f, 0.f, 0.f);
#pragma unroll
    for (int s = 0; s < NSLICE; ++s) {
        const float4 v = *(const float4*)(ws2 + ((size_t)s << 15) + (q << 2));
        acc.x += v.x; acc.y += v.y; acc.z += v.z; acc.w += v.w;
    }
    float s2 = acc.x * acc.x + acc.y * acc.y + acc.z * acc.z + acc.w * acc.w;
    s2 += __shfl_xor(s2, 1);
    s2 += __shfl_xor(s2, 2);
    s2 += __shfl_xor(s2, 4);
    float scale;
    if (mode == 0) {
        scale = rsqrtf(fmaxf(s2, 1e-12f));
    } else {
        scale = (s2 / (1.f + s2)) / sqrtf(s2 + 1e-7f);
    }
    float4 o;
    o.x = acc.x * scale; o.y = acc.y * scale;
    o.z = acc.z * scale; o.w = acc.w * scale;
    *(float4*)(dst + ((size_t)q << 2)) = o;
}

extern "C" void kernel_launch(void* const* d_in, const int* in_sizes, int n_in,
                              void* d_out, int out_size, void* d_ws, size_t ws_size,
                              hipStream_t stream)
{
    const float* u = (const float*)d_in[0];   // (32, 2048, 16)
    const float* W = (const float*)d_in[1];   // (2048, 16, 1024)
    float* out = (float*)d_out;               // (32, 32, 32)

    // ws layout: part (256*32768 fl = 32 MB) | ws2 (1 MB) | onorm (128 KB)
    float* part  = (float*)d_ws;
    float* ws2   = part + (size_t)256 * OSZ;
    float* onorm = ws2 + (size_t)NSLICE * OSZ;

    // onorm = 0 => logits 0 => softmax uniform 1/32 (exactly iteration 0)
    hipMemsetAsync(onorm, 0, (size_t)OSZ * sizeof(float), stream);

    for (int it = 0; it < 3; ++it) {
        caps_stage<<<2 * (NN / NPB), 1024, 0, stream>>>(u, W, onorm, part);
        caps_reduce1<<<256, 256, 0, stream>>>(part, ws2);
        if (it < 2)
            caps_reduce2<<<32, 256, 0, stream>>>(ws2, onorm, 0);  // l2-normalize
        else
            caps_reduce2<<<32, 256, 0, stream>>>(ws2, out, 1);    // squash -> d_out
    }
}